// Round 4
// baseline (143.802 us; speedup 1.0000x reference)
//
#include <hip/hip_runtime.h>
#include <hip/hip_bf16.h>

#define N 8192
#define D 256
#define NCLS 512
#define INV_TEMP 14.285714285714286f      // 1/0.07
#define C1 20.609929155f                  // INV_TEMP * log2(e)
#define JSPLIT 16                         // j-sweep split; grid = (N/128, JSPLIT)

typedef __bf16 bf16x8 __attribute__((ext_vector_type(8)));
typedef float f32x4 __attribute__((ext_vector_type(4)));

static __device__ __forceinline__ unsigned short f2bf(float x) {
    unsigned int u = __float_as_uint(x);
    u = (u + 0x7fffu + ((u >> 16) & 1u)) >> 16;
    return (unsigned short)u;
}
static __device__ __forceinline__ float bf2f(unsigned short b) {
    return __uint_as_float(((unsigned int)b) << 16);
}

// Kernel 1: L2-normalize rows -> bf16 copy; scatter-add bf16-rounded rows into
// per-class sums G (fp32). One wave per row.
__global__ __launch_bounds__(256) void norm_kernel(const float* __restrict__ feat,
                                                   const int* __restrict__ labels,
                                                   __bf16* __restrict__ fb,
                                                   float* __restrict__ G) {
    const int row = (blockIdx.x * 256 + (int)threadIdx.x) >> 6;
    const int lane = threadIdx.x & 63;
    if (row >= N) return;
    float4 v = reinterpret_cast<const float4*>(feat + (size_t)row * D)[lane];
    float ss = v.x * v.x + v.y * v.y + v.z * v.z + v.w * v.w;
#pragma unroll
    for (int m = 1; m < 64; m <<= 1) ss += __shfl_xor(ss, m);
    const float inv = 1.0f / fmaxf(sqrtf(ss), 1e-12f);
    ushort4 o;
    o.x = f2bf(v.x * inv); o.y = f2bf(v.y * inv);
    o.z = f2bf(v.z * inv); o.w = f2bf(v.w * inv);
    reinterpret_cast<ushort4*>(fb + (size_t)row * D)[lane] = o;
    // class-sum scatter of the bf16-rounded values (what MFMA will consume)
    float* g = G + (size_t)labels[row] * D + lane * 4;
    atomicAdd(&g[0], bf2f(o.x));
    atomicAdd(&g[1], bf2f(o.y));
    atomicAdd(&g[2], bf2f(o.z));
    atomicAdd(&g[3], bf2f(o.w));
}

// Kernel 2: exp-sum sweep only. Block = 128 rows x 512 cols, 4 waves (32 rows each).
// A resident in VGPRs; B (32 cols x 256 k = 16 KB) double-buffered in LDS via
// global_load_lds with XOR-swizzle (granule (row,h) holds global (row, h^(row&7))).
__global__ __launch_bounds__(256, 4) void supcon_main(const __bf16* __restrict__ fb,
                                                      float* __restrict__ rowD) {
    __shared__ __align__(1024) char lds[32768];  // 2 x 16 KB B buffers
    const int lane = threadIdx.x & 63;
    const int w = threadIdx.x >> 6;
    const int l4 = lane & 15;
    const int lh = lane >> 4;                 // 0..3
    const int wrow = blockIdx.x * 128 + w * 32;
    const int jbase = blockIdx.y * (N / JSPLIT);
    const char* fbb = (const char*)fb;        // 512 B per row

    // A fragments: wave's 32 rows, full K. lane holds row=(l4), k-bytes k*64+lh*16.
    bf16x8 a[2][8];
#pragma unroll
    for (int mf = 0; mf < 2; ++mf)
#pragma unroll
        for (int k = 0; k < 8; ++k)
            a[mf][k] = *reinterpret_cast<const bf16x8*>(
                fbb + (size_t)(wrow + mf * 16 + l4) * 512 + k * 64 + lh * 16);

    // Swizzled LDS read bases (see R2 derivation): two bases + const offsets.
    const int s7 = l4 & 7;
    const int lhx = lh ^ (s7 & 3);
    const int b2v = (s7 >> 2) & 1;
    const int rb_common = l4 * 512 + lhx * 16;

    auto stage = [&](int bufsel, int jb) {
#pragma unroll
        for (int r = 0; r < 4; ++r) {
            const int G = r * 256 + (int)threadIdx.x;
            const int row = G >> 5, h = G & 31;
            const char* src = fbb + (size_t)(jb + row) * 512 + ((h ^ (row & 7)) * 16);
            char* dst = lds + bufsel * 16384 + r * 4096 + w * 1024;  // wave-uniform
            __builtin_amdgcn_global_load_lds(
                (const __attribute__((address_space(1))) void*)src,
                (__attribute__((address_space(3))) void*)dst, 16, 0, 0);
        }
    };

    float dsum[2][4] = {};

    const int njt = (N / JSPLIT) / 32;  // 16
    int cur = 0;
    stage(0, jbase);
    __syncthreads();

    for (int jt = 0; jt < njt; ++jt) {
        const int jb = jbase + jt * 32;
        if (jt + 1 < njt) stage(cur ^ 1, jb + 32);

        const char* bb = lds + cur * 16384 + rb_common;
        const char* rb0 = bb + b2v * 64;          // k even
        const char* rb1 = bb + 64 - b2v * 64;     // k odd

        f32x4 c[2][2] = {};
#pragma unroll
        for (int q = 0; q < 4; ++q) {
            bf16x8 b00 = *(const bf16x8*)(rb0 + q * 128);         // cf=0, k=2q
            bf16x8 b01 = *(const bf16x8*)(rb0 + 8192 + q * 128);  // cf=1, k=2q
            bf16x8 b10 = *(const bf16x8*)(rb1 + q * 128);         // cf=0, k=2q+1
            bf16x8 b11 = *(const bf16x8*)(rb1 + 8192 + q * 128);  // cf=1, k=2q+1
            c[0][0] = __builtin_amdgcn_mfma_f32_16x16x32_bf16(a[0][2 * q], b00, c[0][0], 0, 0, 0);
            c[1][0] = __builtin_amdgcn_mfma_f32_16x16x32_bf16(a[1][2 * q], b00, c[1][0], 0, 0, 0);
            c[0][1] = __builtin_amdgcn_mfma_f32_16x16x32_bf16(a[0][2 * q], b01, c[0][1], 0, 0, 0);
            c[1][1] = __builtin_amdgcn_mfma_f32_16x16x32_bf16(a[1][2 * q], b01, c[1][1], 0, 0, 0);
            c[0][0] = __builtin_amdgcn_mfma_f32_16x16x32_bf16(a[0][2 * q + 1], b10, c[0][0], 0, 0, 0);
            c[1][0] = __builtin_amdgcn_mfma_f32_16x16x32_bf16(a[1][2 * q + 1], b10, c[1][0], 0, 0, 0);
            c[0][1] = __builtin_amdgcn_mfma_f32_16x16x32_bf16(a[0][2 * q + 1], b11, c[0][1], 0, 0, 0);
            c[1][1] = __builtin_amdgcn_mfma_f32_16x16x32_bf16(a[1][2 * q + 1], b11, c[1][1], 0, 0, 0);
        }

        // epilogue: pure exp-sum; diagonal handled only in the (rare) diag fragments
#pragma unroll
        for (int mf = 0; mf < 2; ++mf) {
#pragma unroll
            for (int cf = 0; cf < 2; ++cf) {
                const f32x4 cc = c[mf][cf];
                if (wrow + mf * 16 == jb + cf * 16) {  // wave-uniform: diag fragment
#pragma unroll
                    for (int r = 0; r < 4; ++r) {
                        const bool diag = (l4 == lh * 4 + r);
                        dsum[mf][r] += diag ? 0.0f : __builtin_amdgcn_exp2f(cc[r] * C1);
                    }
                } else {
#pragma unroll
                    for (int r = 0; r < 4; ++r)
                        dsum[mf][r] += __builtin_amdgcn_exp2f(cc[r] * C1);
                }
            }
        }
        __syncthreads();  // stage(jt+1) drained; all waves done reading buf[cur]
        cur ^= 1;
    }

    // 16-lane (l4) reduction, then 1 atomic per row
#pragma unroll
    for (int mf = 0; mf < 2; ++mf) {
#pragma unroll
        for (int r = 0; r < 4; ++r) {
            float v1 = dsum[mf][r];
#pragma unroll
            for (int m = 1; m < 16; m <<= 1) v1 += __shfl_xor(v1, m);
            if (l4 == 0) atomicAdd(&rowD[wrow + mf * 16 + lh * 4 + r], v1);
        }
    }
}

// Kernel 3: rowS[i] = (f_i . G[lab_i] - f_i . f_i) / T. One wave per row.
__global__ __launch_bounds__(256) void rowdot_kernel(const __bf16* __restrict__ fb,
                                                     const int* __restrict__ labels,
                                                     const float* __restrict__ G,
                                                     float* __restrict__ rowS) {
    const int row = (blockIdx.x * 256 + (int)threadIdx.x) >> 6;
    const int lane = threadIdx.x & 63;
    if (row >= N) return;
    ushort4 o = reinterpret_cast<const ushort4*>(fb + (size_t)row * D)[lane];
    const float f0 = bf2f(o.x), f1 = bf2f(o.y), f2 = bf2f(o.z), f3 = bf2f(o.w);
    const float4 g = reinterpret_cast<const float4*>(G + (size_t)labels[row] * D)[lane];
    float dot = f0 * g.x + f1 * g.y + f2 * g.z + f3 * g.w;
    float self = f0 * f0 + f1 * f1 + f2 * f2 + f3 * f3;
#pragma unroll
    for (int m = 1; m < 64; m <<= 1) {
        dot += __shfl_xor(dot, m);
        self += __shfl_xor(self, m);
    }
    if (lane == 0) rowS[row] = (dot - self) * INV_TEMP;
}

// Kernel 4: label histogram (positive counts) + fold per-row stats into the loss.
__global__ __launch_bounds__(256) void finalize_kernel(const int* __restrict__ labels,
                                                       const float* __restrict__ rowD,
                                                       const float* __restrict__ rowS,
                                                       float* __restrict__ out) {
    __shared__ int hist[NCLS];
    __shared__ float red[4];
    for (int i = threadIdx.x; i < NCLS; i += 256) hist[i] = 0;
    __syncthreads();
    for (int i = threadIdx.x; i < N; i += 256) atomicAdd(&hist[labels[i]], 1);
    __syncthreads();
    float local = 0.0f;
    for (int r = threadIdx.x; r < N; r += 256) {
        const float c = (float)(hist[labels[r]] - 1);
        local += (rowS[r] - c * __logf(rowD[r] + 1e-6f)) / fmaxf(c, 1.0f);
    }
#pragma unroll
    for (int m = 1; m < 64; m <<= 1) local += __shfl_xor(local, m);
    if ((threadIdx.x & 63) == 0) red[threadIdx.x >> 6] = local;
    __syncthreads();
    if (threadIdx.x == 0) out[0] = -(red[0] + red[1] + red[2] + red[3]) / (float)N;
}

extern "C" void kernel_launch(void* const* d_in, const int* in_sizes, int n_in,
                              void* d_out, int out_size, void* d_ws, size_t ws_size,
                              hipStream_t stream) {
    const float* feat = (const float*)d_in[0];
    const int* labels = (const int*)d_in[1];

    // ws layout: fb 4MB | G 512KB | rowD 32KB | rowS 32KB
    __bf16* fb = (__bf16*)d_ws;
    float* G = (float*)((char*)d_ws + (size_t)N * D * 2);
    float* rowD = G + (size_t)NCLS * D;
    float* rowS = rowD + N;

    hipMemsetAsync(G, 0, ((size_t)NCLS * D + N) * sizeof(float), stream);  // G + rowD
    norm_kernel<<<N / 4, 256, 0, stream>>>(feat, labels, fb, G);
    dim3 grid(N / 128, JSPLIT);
    supcon_main<<<grid, 256, 0, stream>>>(fb, rowD);
    rowdot_kernel<<<N / 4, 256, 0, stream>>>(fb, labels, G, rowS);
    finalize_kernel<<<1, 256, 0, stream>>>(labels, rowD, rowS, (float*)d_out);
}

// Round 5
// 126.654 us; speedup vs baseline: 1.1354x; 1.1354x over previous
//
#include <hip/hip_runtime.h>
#include <hip/hip_bf16.h>

#define N 8192
#define D 256
#define NCLS 512
#define INV_TEMP 14.285714285714286f      // 1/0.07
#define C1 20.609929155f                  // INV_TEMP * log2(e)
#define JSPLIT 16                         // j-sweep split; grid = (32, JSPLIT)

typedef __bf16 bf16x8 __attribute__((ext_vector_type(8)));
typedef float f32x4 __attribute__((ext_vector_type(4)));

static __device__ __forceinline__ unsigned short f2bf(float x) {
    unsigned int u = __float_as_uint(x);
    u = (u + 0x7fffu + ((u >> 16) & 1u)) >> 16;
    return (unsigned short)u;
}
static __device__ __forceinline__ float bf2f(unsigned short b) {
    return __uint_as_float(((unsigned int)b) << 16);
}

// Kernel 1: L2-normalize rows -> bf16 copy; zero rowD. One wave per row.
__global__ __launch_bounds__(256) void norm_kernel(const float* __restrict__ feat,
                                                   __bf16* __restrict__ fb,
                                                   float* __restrict__ rowD) {
    const int gt = blockIdx.x * 256 + (int)threadIdx.x;
    if (gt < N) rowD[gt] = 0.0f;
    const int row = gt >> 6;
    const int lane = threadIdx.x & 63;
    if (row >= N) return;
    float4 v = reinterpret_cast<const float4*>(feat + (size_t)row * D)[lane];
    float ss = v.x * v.x + v.y * v.y + v.z * v.z + v.w * v.w;
#pragma unroll
    for (int m = 1; m < 64; m <<= 1) ss += __shfl_xor(ss, m);
    const float inv = 1.0f / fmaxf(sqrtf(ss), 1e-12f);
    ushort4 o;
    o.x = f2bf(v.x * inv); o.y = f2bf(v.y * inv);
    o.z = f2bf(v.z * inv); o.w = f2bf(v.w * inv);
    reinterpret_cast<ushort4*>(fb + (size_t)row * D)[lane] = o;
}

// Kernel 2: per-class sums G[c] = sum of bf16-rounded normalized rows with label c.
// 256 blocks x 2 classes; 4 waves quarter-scan rows via ballot (wave-uniform inner
// loops, no atomics); lane l accumulates dims 4l..4l+3.
__global__ __launch_bounds__(256) void classsum_kernel(const __bf16* __restrict__ fb,
                                                       const int* __restrict__ labels,
                                                       float* __restrict__ G) {
    const int lane = threadIdx.x & 63;
    const int w = threadIdx.x >> 6;
    const int c0 = blockIdx.x * 2, c1 = c0 + 1;
    float4 a0 = {0, 0, 0, 0}, a1 = {0, 0, 0, 0};
    const int rbase = w * (N / 4);
    for (int chunk = 0; chunk < N / 4; chunk += 64) {
        const int lab = labels[rbase + chunk + lane];
        unsigned long long m0 = __ballot(lab == c0);
        unsigned long long m1 = __ballot(lab == c1);
        while (m0) {
            const int r = rbase + chunk + __builtin_ctzll(m0);
            m0 &= m0 - 1;
            ushort4 o = reinterpret_cast<const ushort4*>(fb + (size_t)r * D)[lane];
            a0.x += bf2f(o.x); a0.y += bf2f(o.y); a0.z += bf2f(o.z); a0.w += bf2f(o.w);
        }
        while (m1) {
            const int r = rbase + chunk + __builtin_ctzll(m1);
            m1 &= m1 - 1;
            ushort4 o = reinterpret_cast<const ushort4*>(fb + (size_t)r * D)[lane];
            a1.x += bf2f(o.x); a1.y += bf2f(o.y); a1.z += bf2f(o.z); a1.w += bf2f(o.w);
        }
    }
    __shared__ float4 part[4][2][64];
    part[w][0][lane] = a0;
    part[w][1][lane] = a1;
    __syncthreads();
    if (w < 2) {
        float4 s = part[0][w][lane];
        const float4 p1 = part[1][w][lane], p2 = part[2][w][lane], p3 = part[3][w][lane];
        s.x += p1.x + p2.x + p3.x;
        s.y += p1.y + p2.y + p3.y;
        s.z += p1.z + p2.z + p3.z;
        s.w += p1.w + p2.w + p3.w;
        reinterpret_cast<float4*>(G + (size_t)(c0 + w) * D)[lane] = s;
    }
}

// Kernel 3: exp-sum sweep. Block = 256 rows x 512 cols, 4 waves (64 rows each).
// A resident in VGPRs (a[4][8]); B (32 cols x 256 k = 16 KB) double-buffered in LDS
// via global_load_lds with XOR-swizzle (granule (row,h) holds global (row, h^(row&7))).
__global__ __launch_bounds__(256, 2) void supcon_main(const __bf16* __restrict__ fb,
                                                      float* __restrict__ rowD) {
    __shared__ __align__(1024) char lds[32768];  // 2 x 16 KB B buffers
    const int lane = threadIdx.x & 63;
    const int w = threadIdx.x >> 6;
    const int l4 = lane & 15;
    const int lh = lane >> 4;                 // 0..3
    const int wrow = blockIdx.x * 256 + w * 64;
    const int jbase = blockIdx.y * (N / JSPLIT);
    const char* fbb = (const char*)fb;        // 512 B per row

    // A fragments: wave's 64 rows, full K. lane holds row=(l4), k-bytes k*64+lh*16.
    bf16x8 a[4][8];
#pragma unroll
    for (int mf = 0; mf < 4; ++mf)
#pragma unroll
        for (int k = 0; k < 8; ++k)
            a[mf][k] = *reinterpret_cast<const bf16x8*>(
                fbb + (size_t)(wrow + mf * 16 + l4) * 512 + k * 64 + lh * 16);

    // Swizzled LDS read bases (R2 derivation): two bases + const offsets.
    const int s7 = l4 & 7;
    const int lhx = lh ^ (s7 & 3);
    const int b2v = (s7 >> 2) & 1;
    const int rb_common = l4 * 512 + lhx * 16;

    auto stage = [&](int bufsel, int jb) {
#pragma unroll
        for (int r = 0; r < 4; ++r) {
            const int gidx = r * 256 + (int)threadIdx.x;
            const int row = gidx >> 5, h = gidx & 31;
            const char* src = fbb + (size_t)(jb + row) * 512 + ((h ^ (row & 7)) * 16);
            char* dst = lds + bufsel * 16384 + r * 4096 + w * 1024;  // wave-uniform
            __builtin_amdgcn_global_load_lds(
                (const __attribute__((address_space(1))) void*)src,
                (__attribute__((address_space(3))) void*)dst, 16, 0, 0);
        }
    };

    float dsum[4][4] = {};

    const int njt = (N / JSPLIT) / 32;  // 16
    int cur = 0;
    stage(0, jbase);
    __syncthreads();

    for (int jt = 0; jt < njt; ++jt) {
        const int jb = jbase + jt * 32;
        if (jt + 1 < njt) stage(cur ^ 1, jb + 32);

        const char* bb = lds + cur * 16384 + rb_common;
        const char* rb0 = bb + b2v * 64;          // k even
        const char* rb1 = bb + 64 - b2v * 64;     // k odd

        f32x4 c[4][2] = {};
#pragma unroll
        for (int q = 0; q < 4; ++q) {
            bf16x8 b00 = *(const bf16x8*)(rb0 + q * 128);         // cf=0, k=2q
            bf16x8 b01 = *(const bf16x8*)(rb0 + 8192 + q * 128);  // cf=1, k=2q
            bf16x8 b10 = *(const bf16x8*)(rb1 + q * 128);         // cf=0, k=2q+1
            bf16x8 b11 = *(const bf16x8*)(rb1 + 8192 + q * 128);  // cf=1, k=2q+1
#pragma unroll
            for (int mf = 0; mf < 4; ++mf) {
                c[mf][0] = __builtin_amdgcn_mfma_f32_16x16x32_bf16(a[mf][2 * q], b00, c[mf][0], 0, 0, 0);
                c[mf][1] = __builtin_amdgcn_mfma_f32_16x16x32_bf16(a[mf][2 * q], b01, c[mf][1], 0, 0, 0);
                c[mf][0] = __builtin_amdgcn_mfma_f32_16x16x32_bf16(a[mf][2 * q + 1], b10, c[mf][0], 0, 0, 0);
                c[mf][1] = __builtin_amdgcn_mfma_f32_16x16x32_bf16(a[mf][2 * q + 1], b11, c[mf][1], 0, 0, 0);
            }
        }

        // epilogue: pure exp-sum; diagonal handled only in the (rare) diag fragments
#pragma unroll
        for (int mf = 0; mf < 4; ++mf) {
#pragma unroll
            for (int cf = 0; cf < 2; ++cf) {
                const f32x4 cc = c[mf][cf];
                if (wrow + mf * 16 == jb + cf * 16) {  // wave-uniform: diag fragment
#pragma unroll
                    for (int r = 0; r < 4; ++r) {
                        const bool diag = (l4 == lh * 4 + r);
                        dsum[mf][r] += diag ? 0.0f : __builtin_amdgcn_exp2f(cc[r] * C1);
                    }
                } else {
#pragma unroll
                    for (int r = 0; r < 4; ++r)
                        dsum[mf][r] += __builtin_amdgcn_exp2f(cc[r] * C1);
                }
            }
        }
        __syncthreads();  // stage(jt+1) drained; all waves done reading buf[cur]
        cur ^= 1;
    }

    // 16-lane (l4) reduction, then 1 atomic per row
#pragma unroll
    for (int mf = 0; mf < 4; ++mf) {
#pragma unroll
        for (int r = 0; r < 4; ++r) {
            float v1 = dsum[mf][r];
#pragma unroll
            for (int m = 1; m < 16; m <<= 1) v1 += __shfl_xor(v1, m);
            if (l4 == 0) atomicAdd(&rowD[wrow + mf * 16 + lh * 4 + r], v1);
        }
    }
}

// Kernel 4: rowS[i] = (f_i . G[lab_i] - f_i . f_i) / T. One wave per row.
__global__ __launch_bounds__(256) void rowdot_kernel(const __bf16* __restrict__ fb,
                                                     const int* __restrict__ labels,
                                                     const float* __restrict__ G,
                                                     float* __restrict__ rowS) {
    const int row = (blockIdx.x * 256 + (int)threadIdx.x) >> 6;
    const int lane = threadIdx.x & 63;
    if (row >= N) return;
    ushort4 o = reinterpret_cast<const ushort4*>(fb + (size_t)row * D)[lane];
    const float f0 = bf2f(o.x), f1 = bf2f(o.y), f2 = bf2f(o.z), f3 = bf2f(o.w);
    const float4 g = reinterpret_cast<const float4*>(G + (size_t)labels[row] * D)[lane];
    float dot = f0 * g.x + f1 * g.y + f2 * g.z + f3 * g.w;
    float self = f0 * f0 + f1 * f1 + f2 * f2 + f3 * f3;
#pragma unroll
    for (int m = 1; m < 64; m <<= 1) {
        dot += __shfl_xor(dot, m);
        self += __shfl_xor(self, m);
    }
    if (lane == 0) rowS[row] = (dot - self) * INV_TEMP;
}

// Kernel 5: label histogram (positive counts) + fold per-row stats into the loss.
__global__ __launch_bounds__(256) void finalize_kernel(const int* __restrict__ labels,
                                                       const float* __restrict__ rowD,
                                                       const float* __restrict__ rowS,
                                                       float* __restrict__ out) {
    __shared__ int hist[NCLS];
    __shared__ float red[4];
    for (int i = threadIdx.x; i < NCLS; i += 256) hist[i] = 0;
    __syncthreads();
    for (int i = threadIdx.x; i < N; i += 256) atomicAdd(&hist[labels[i]], 1);
    __syncthreads();
    float local = 0.0f;
    for (int r = threadIdx.x; r < N; r += 256) {
        const float c = (float)(hist[labels[r]] - 1);
        local += (rowS[r] - c * __logf(rowD[r] + 1e-6f)) / fmaxf(c, 1.0f);
    }
#pragma unroll
    for (int m = 1; m < 64; m <<= 1) local += __shfl_xor(local, m);
    if ((threadIdx.x & 63) == 0) red[threadIdx.x >> 6] = local;
    __syncthreads();
    if (threadIdx.x == 0) out[0] = -(red[0] + red[1] + red[2] + red[3]) / (float)N;
}

extern "C" void kernel_launch(void* const* d_in, const int* in_sizes, int n_in,
                              void* d_out, int out_size, void* d_ws, size_t ws_size,
                              hipStream_t stream) {
    const float* feat = (const float*)d_in[0];
    const int* labels = (const int*)d_in[1];

    // ws layout: fb 4MB | G 512KB | rowD 32KB | rowS 32KB
    __bf16* fb = (__bf16*)d_ws;
    float* G = (float*)((char*)d_ws + (size_t)N * D * 2);
    float* rowD = G + (size_t)NCLS * D;
    float* rowS = rowD + N;

    norm_kernel<<<N / 4, 256, 0, stream>>>(feat, fb, rowD);
    classsum_kernel<<<NCLS / 2, 256, 0, stream>>>(fb, labels, G);
    dim3 grid(N / 256, JSPLIT);
    supcon_main<<<grid, 256, 0, stream>>>(fb, rowD);
    rowdot_kernel<<<N / 4, 256, 0, stream>>>(fb, labels, G, rowS);
    finalize_kernel<<<1, 256, 0, stream>>>(labels, rowD, rowS, (float*)d_out);
}

// Round 6
// 117.647 us; speedup vs baseline: 1.2223x; 1.0766x over previous
//
#include <hip/hip_runtime.h>
#include <hip/hip_bf16.h>

#define N 8192
#define D 256
#define NCLS 512
#define INV_TEMP 14.285714285714286f      // 1/0.07
#define C1 20.609929155f                  // INV_TEMP * log2(e)
#define JSPLIT 16                         // j-sweep split; grid = (32, JSPLIT)

typedef __bf16 bf16x8 __attribute__((ext_vector_type(8)));
typedef float f32x4 __attribute__((ext_vector_type(4)));

static __device__ __forceinline__ unsigned short f2bf(float x) {
    unsigned int u = __float_as_uint(x);
    u = (u + 0x7fffu + ((u >> 16) & 1u)) >> 16;
    return (unsigned short)u;
}
static __device__ __forceinline__ float bf2f(unsigned short b) {
    return __uint_as_float(((unsigned int)b) << 16);
}

// Kernel 1: L2-normalize rows -> bf16 copy; zero rowD/rowS (2N floats). One wave/row.
__global__ __launch_bounds__(256) void norm_kernel(const float* __restrict__ feat,
                                                   __bf16* __restrict__ fb,
                                                   float* __restrict__ rowDS) {
    const int gt = blockIdx.x * 256 + (int)threadIdx.x;
    if (gt < 2 * N) rowDS[gt] = 0.0f;
    const int row = gt >> 6;
    const int lane = threadIdx.x & 63;
    if (row >= N) return;
    float4 v = reinterpret_cast<const float4*>(feat + (size_t)row * D)[lane];
    float ss = v.x * v.x + v.y * v.y + v.z * v.z + v.w * v.w;
#pragma unroll
    for (int m = 1; m < 64; m <<= 1) ss += __shfl_xor(ss, m);
    const float inv = 1.0f / fmaxf(sqrtf(ss), 1e-12f);
    ushort4 o;
    o.x = f2bf(v.x * inv); o.y = f2bf(v.y * inv);
    o.z = f2bf(v.z * inv); o.w = f2bf(v.w * inv);
    reinterpret_cast<ushort4*>(fb + (size_t)row * D)[lane] = o;
}

// Kernel 2: exp-sum + masked-logit-sum sweep. Block = 256 rows x 512 cols, 4 waves
// (64 rows each). A resident in VGPRs (a[4][8]); B (32 cols x 256 k = 16 KB)
// double-buffered in LDS via global_load_lds with XOR-swizzle
// (granule (row,h) holds global (row, h^(row&7))).
__global__ __launch_bounds__(256, 2) void supcon_main(const __bf16* __restrict__ fb,
                                                      const int* __restrict__ labels,
                                                      float* __restrict__ rowD,
                                                      float* __restrict__ rowS) {
    __shared__ __align__(1024) char lds[32768];  // 2 x 16 KB B buffers
    const int lane = threadIdx.x & 63;
    const int w = threadIdx.x >> 6;
    const int l4 = lane & 15;
    const int lh = lane >> 4;                 // 0..3
    const int wrow = blockIdx.x * 256 + w * 64;
    const int jbase = blockIdx.y * (N / JSPLIT);
    const char* fbb = (const char*)fb;        // 512 B per row

    // A fragments: wave's 64 rows, full K. lane holds row=(l4), k-bytes k*64+lh*16.
    bf16x8 a[4][8];
#pragma unroll
    for (int mf = 0; mf < 4; ++mf)
#pragma unroll
        for (int k = 0; k < 8; ++k)
            a[mf][k] = *reinterpret_cast<const bf16x8*>(
                fbb + (size_t)(wrow + mf * 16 + l4) * 512 + k * 64 + lh * 16);

    // labels of the rows this lane's accumulators cover (C row = lh*4 + r)
    int labi[4][4];
#pragma unroll
    for (int mf = 0; mf < 4; ++mf)
#pragma unroll
        for (int r = 0; r < 4; ++r) labi[mf][r] = labels[wrow + mf * 16 + lh * 4 + r];

    // Swizzled LDS read bases (R2 derivation): two bases + const offsets.
    const int s7 = l4 & 7;
    const int lhx = lh ^ (s7 & 3);
    const int b2v = (s7 >> 2) & 1;
    const int rb_common = l4 * 512 + lhx * 16;

    auto stage = [&](int bufsel, int jb) {
#pragma unroll
        for (int r = 0; r < 4; ++r) {
            const int gidx = r * 256 + (int)threadIdx.x;
            const int row = gidx >> 5, h = gidx & 31;
            const char* src = fbb + (size_t)(jb + row) * 512 + ((h ^ (row & 7)) * 16);
            char* dst = lds + bufsel * 16384 + r * 4096 + w * 1024;  // wave-uniform
            __builtin_amdgcn_global_load_lds(
                (const __attribute__((address_space(1))) void*)src,
                (__attribute__((address_space(3))) void*)dst, 16, 0, 0);
        }
    };

    float dsum[4][4] = {};
    float ssum[4][4] = {};

    const int njt = (N / JSPLIT) / 32;  // 16
    int cur = 0;
    stage(0, jbase);
    __syncthreads();

    for (int jt = 0; jt < njt; ++jt) {
        const int jb = jbase + jt * 32;
        if (jt + 1 < njt) stage(cur ^ 1, jb + 32);

        int labj[2];
        labj[0] = labels[jb + l4];
        labj[1] = labels[jb + 16 + l4];

        const char* bb = lds + cur * 16384 + rb_common;
        const char* rb0 = bb + b2v * 64;          // k even
        const char* rb1 = bb + 64 - b2v * 64;     // k odd

        f32x4 c[4][2] = {};
#pragma unroll
        for (int q = 0; q < 4; ++q) {
            bf16x8 b00 = *(const bf16x8*)(rb0 + q * 128);         // cf=0, k=2q
            bf16x8 b01 = *(const bf16x8*)(rb0 + 8192 + q * 128);  // cf=1, k=2q
            bf16x8 b10 = *(const bf16x8*)(rb1 + q * 128);         // cf=0, k=2q+1
            bf16x8 b11 = *(const bf16x8*)(rb1 + 8192 + q * 128);  // cf=1, k=2q+1
#pragma unroll
            for (int mf = 0; mf < 4; ++mf) {
                c[mf][0] = __builtin_amdgcn_mfma_f32_16x16x32_bf16(a[mf][2 * q], b00, c[mf][0], 0, 0, 0);
                c[mf][1] = __builtin_amdgcn_mfma_f32_16x16x32_bf16(a[mf][2 * q], b01, c[mf][1], 0, 0, 0);
                c[mf][0] = __builtin_amdgcn_mfma_f32_16x16x32_bf16(a[mf][2 * q + 1], b10, c[mf][0], 0, 0, 0);
                c[mf][1] = __builtin_amdgcn_mfma_f32_16x16x32_bf16(a[mf][2 * q + 1], b11, c[mf][1], 0, 0, 0);
            }
        }

        // epilogue: exp-sum + masked raw-dot sum; diag only in the diag fragments
#pragma unroll
        for (int mf = 0; mf < 4; ++mf) {
#pragma unroll
            for (int cf = 0; cf < 2; ++cf) {
                const f32x4 cc = c[mf][cf];
                if (wrow + mf * 16 == jb + cf * 16) {  // wave-uniform: diag fragment
#pragma unroll
                    for (int r = 0; r < 4; ++r) {
                        const float t = cc[r];
                        const bool diag = (l4 == lh * 4 + r);
                        dsum[mf][r] += diag ? 0.0f : __builtin_amdgcn_exp2f(t * C1);
                        const bool pos = (labi[mf][r] == labj[cf]) && !diag;
                        ssum[mf][r] += pos ? t : 0.0f;
                    }
                } else {
#pragma unroll
                    for (int r = 0; r < 4; ++r) {
                        const float t = cc[r];
                        dsum[mf][r] += __builtin_amdgcn_exp2f(t * C1);
                        ssum[mf][r] += (labi[mf][r] == labj[cf]) ? t : 0.0f;
                    }
                }
            }
        }
        __syncthreads();  // stage(jt+1) drained; all waves done reading buf[cur]
        cur ^= 1;
    }

    // 16-lane (l4) reduction, then 2 atomics per row
#pragma unroll
    for (int mf = 0; mf < 4; ++mf) {
#pragma unroll
        for (int r = 0; r < 4; ++r) {
            float v1 = dsum[mf][r], v2 = ssum[mf][r];
#pragma unroll
            for (int m = 1; m < 16; m <<= 1) {
                v1 += __shfl_xor(v1, m);
                v2 += __shfl_xor(v2, m);
            }
            if (l4 == 0) {
                const int rg = wrow + mf * 16 + lh * 4 + r;
                atomicAdd(&rowD[rg], v1);
                atomicAdd(&rowS[rg], v2 * INV_TEMP);
            }
        }
    }
}

// Kernel 3: label histogram (positive counts) + fold per-row stats into the loss.
__global__ __launch_bounds__(256) void finalize_kernel(const int* __restrict__ labels,
                                                       const float* __restrict__ rowD,
                                                       const float* __restrict__ rowS,
                                                       float* __restrict__ out) {
    __shared__ int hist[NCLS];
    __shared__ float red[4];
    for (int i = threadIdx.x; i < NCLS; i += 256) hist[i] = 0;
    __syncthreads();
    for (int i = threadIdx.x; i < N; i += 256) atomicAdd(&hist[labels[i]], 1);
    __syncthreads();
    float local = 0.0f;
    for (int r = threadIdx.x; r < N; r += 256) {
        const float c = (float)(hist[labels[r]] - 1);
        local += (rowS[r] - c * __logf(rowD[r] + 1e-6f)) / fmaxf(c, 1.0f);
    }
#pragma unroll
    for (int m = 1; m < 64; m <<= 1) local += __shfl_xor(local, m);
    if ((threadIdx.x & 63) == 0) red[threadIdx.x >> 6] = local;
    __syncthreads();
    if (threadIdx.x == 0) out[0] = -(red[0] + red[1] + red[2] + red[3]) / (float)N;
}

extern "C" void kernel_launch(void* const* d_in, const int* in_sizes, int n_in,
                              void* d_out, int out_size, void* d_ws, size_t ws_size,
                              hipStream_t stream) {
    const float* feat = (const float*)d_in[0];
    const int* labels = (const int*)d_in[1];

    // ws layout: fb 4MB | rowD 32KB | rowS 32KB
    __bf16* fb = (__bf16*)d_ws;
    float* rowD = (float*)((char*)d_ws + (size_t)N * D * 2);
    float* rowS = rowD + N;

    norm_kernel<<<N / 4, 256, 0, stream>>>(feat, fb, rowD);
    dim3 grid(N / 256, JSPLIT);
    supcon_main<<<grid, 256, 0, stream>>>(fb, labels, rowD, rowS);
    finalize_kernel<<<1, 256, 0, stream>>>(labels, rowD, rowS, (float*)d_out);
}